// Round 6
// baseline (33.861 us; speedup 1.0000x reference)
//
#include <hip/hip_runtime.h>

#define NPART 2048
#define KMAX 256
#define CUT2 0.09f
#define NW 4                        // waves per center (1 block = 1 center)
#define SEG (NPART / NW)            // 512 particles per wave segment
#define RPW (SEG / 64)              // 8 rounds per wave

__global__ __launch_bounds__(256) void nbr_kernel(
    const float* __restrict__ pos,
    int* __restrict__ out_neigh,
    int* __restrict__ out_cell,
    int* __restrict__ out_max)
{
#pragma clang fp contract(off)
    __shared__ int cnt[27][NW];            // per-(cell,wave) hit counts
    __shared__ unsigned short myl[KMAX];   // hit list: j = s*2048+p (<55296)

    const int t    = threadIdx.x;
    const int wave = t >> 6;
    const int lane = t & 63;
    const int i    = blockIdx.x;           // this block's center
    const int pb   = wave * SEG;           // wave's particle segment base

    // register-resident segment: 24 batched loads, one vmcnt wait at use
    float px[RPW], py[RPW], pz[RPW];
#pragma unroll
    for (int u = 0; u < RPW; ++u) {
        const int p = pb + (u << 6) + lane;
        px[u] = pos[3 * p + 0];
        py[u] = pos[3 * p + 1];
        pz[u] = pos[3 * p + 2];
    }
    const float cx = pos[3 * i + 0];       // broadcast via cache
    const float cy = pos[3 * i + 1];
    const float cz = pos[3 * i + 2];

    // wave-uniform cell prune: min distance from center to shifted unit box
    unsigned int amask = 0;
#pragma clang loop unroll(disable)
    for (int s = 0; s < 27; ++s) {
        const int s3 = s / 3, s9 = s / 9;
        const float fx = (float)(s - 3 * s3 - 1);
        const float fy = (float)(s3 - 3 * s9 - 1);
        const float fz = (float)(s9 - 1);
        const float dx = fmaxf(fmaxf(fx - cx, cx - (fx + 1.0f)), 0.0f);
        const float dy = fmaxf(fmaxf(fy - cy, cy - (fy + 1.0f)), 0.0f);
        const float dz = fmaxf(fmaxf(fz - cz, cz - (fz + 1.0f)), 0.0f);
        const float dmin2 = dx * dx + dy * dy + dz * dz;
        if (dmin2 <= 0.0901f) amask |= (1u << s);   // margin >> f32 rounding
    }
    amask = __builtin_amdgcn_readfirstlane(amask);  // identical across block

    int total = 0;                         // running center-wide hit count

    // hot loop: ONE code copy (s-loop not unrolled) -> L1I-resident
#pragma clang loop unroll(disable)
    for (int s = 0; s < 27; ++s) {
        if (!((amask >> s) & 1u)) continue;          // block-uniform skip
        const int s3 = s / 3, s9 = s / 9;
        const int cxi = s - 3 * s3 - 1;
        const int cyi = s3 - 3 * s9 - 1;
        const int czi = s9 - 1;
        const float fx = (float)cxi, fy = (float)cyi, fz = (float)czi;
        const bool selfcell = (s == 13);

        // eval: 8 register rounds, save ballots
        unsigned long long m[RPW];
        int mycnt = 0;
#pragma unroll
        for (int u = 0; u < RPW; ++u) {
            const int p = pb + (u << 6) + lane;
            // exact reference op order: n = shift + p ; d = n - c ; no fma
            const float nx = fx + px[u];
            const float ny = fy + py[u];
            const float nz = fz + pz[u];
            const float dx = nx - cx;
            const float dy = ny - cy;
            const float dz = nz - cz;
            const float d2 = (dx * dx + dy * dy) + dz * dz;
            bool hit = (d2 <= CUT2);
            if (selfcell && p == i) hit = false;
            m[u] = __ballot(hit);
            mycnt += (int)__popcll(m[u]);
        }

        // merge: publish per-wave count, single barrier, compute bases
        if (lane == 0) cnt[s][wave] = mycnt;
        __syncthreads();
        const int c0 = cnt[s][0], c1 = cnt[s][1];
        const int c2 = cnt[s][2], c3 = cnt[s][3];
        int base = total;
        if (wave > 0) base += c0;
        if (wave > 1) base += c1;
        if (wave > 2) base += c2;
        total += c0 + c1 + c2 + c3;

        // write hits in exact j order: segment asc -> round asc -> lane rank
#pragma unroll
        for (int u = 0; u < RPW; ++u) {
            const unsigned long long mu = m[u];
            if ((mu >> lane) & 1ull) {
                const int rank = __popcll(mu & ((1ull << lane) - 1ull));
                const int slot = base + rank;
                if (slot < KMAX)
                    myl[slot] = (unsigned short)((s << 11) + pb + (u << 6) + lane);
            }
            base += (int)__popcll(mu);
        }
    }
    __syncthreads();

    // flush: 256 threads, one slot each; tail fill fused
    // tail: neighbours = -1, cell = shifts[26] = (1,1,1)  (jnp.take wrap)
    const int obase = i * KMAX;
    {
        int nv, cxo, cyo, czo;
        if (t < total) {
            const int j = (int)myl[t];
            const int s = j >> 11;
            const int s3 = s / 3, s9 = s / 9;
            nv  = j & 2047;
            cxo = s - 3 * s3 - 1;
            cyo = s3 - 3 * s9 - 1;
            czo = s9 - 1;
        } else {
            nv = -1; cxo = 1; cyo = 1; czo = 1;
        }
        out_neigh[obase + t] = nv;
        const int cb = (obase + t) * 3;
        out_cell[cb + 0] = cxo;
        out_cell[cb + 1] = cyo;
        out_cell[cb + 2] = czo;
    }

    // actual_max: check-then-atomic (monotone-safe; poison 0xAA = negative ->
    // first replay updates; replays deterministic -> later replays skip).
    if (t == 0) {
        volatile int* vm = (volatile int*)out_max;
        if (total > *vm) atomicMax(out_max, total);
    }
}

extern "C" void kernel_launch(void* const* d_in, const int* in_sizes, int n_in,
                              void* d_out, int out_size, void* d_ws, size_t ws_size,
                              hipStream_t stream)
{
    const float* pos = (const float*)d_in[0];   // (2048,3) f32
    int* out       = (int*)d_out;
    int* out_neigh = out;                        // (2048,256)
    int* out_cell  = out + NPART * KMAX;         // (2048,256,3)
    int* out_max   = out + NPART * KMAX * 4;     // scalar

    nbr_kernel<<<NPART, 256, 0, stream>>>(pos, out_neigh, out_cell, out_max);
}